// Round 17
// baseline (165.291 us; speedup 1.0000x reference)
//
#include <hip/hip_runtime.h>

typedef __attribute__((ext_vector_type(8))) short short8;
typedef __attribute__((ext_vector_type(4))) float floatx4;
typedef unsigned short u16;
typedef unsigned int u32;

#define NB 8
#define CI 512
#define CO 512
#define HH 64
#define WW 64
#define HP 66
#define WP 66

__device__ __forceinline__ u16 f2bf(float f) {
  u32 u = __builtin_bit_cast(u32, f);
  u += 0x7fffu + ((u >> 16) & 1u);
  return (u16)(u >> 16);
}

__device__ __forceinline__ void gload16(const void* g, void* l) {
  __builtin_amdgcn_global_load_lds(
      (const __attribute__((address_space(1))) unsigned int*)g,
      (__attribute__((address_space(3))) unsigned int*)l, 16, 0, 0);
}

// fused prep1: blocks 0..1023 -> style s[b,i]; blocks 1024..2047 -> wprep.
// wprep now writes weights in MFMA FRAGMENT layout:
//   frag(t,g,kk) = 1KB block at u16 offset ((t*32+g)*2+kk)*512,
//   lane l=(k8<<4)|col holds bytes j: A[g*16+col][t*64+kk*32+k8*8+j]
// so conv loads A fragments global->VGPR with lane-contiguous (coalesced) 16B.
__global__ __launch_bounds__(256) void k_prep1(
    const float* __restrict__ y, const float* __restrict__ aw,
    const float* __restrict__ ab, float* __restrict__ s,
    const float* __restrict__ wt, float* __restrict__ wsum,
    u16* __restrict__ wbv)
{
  if (blockIdx.x < 1024) {
    const int wid = blockIdx.x * 4 + (threadIdx.x >> 6);
    const int lane = threadIdx.x & 63;
    const int b = wid >> 9, i = wid & 511;
    float sum = 0.f;
    #pragma unroll
    for (int j = 0; j < 8; ++j) {
      const int k = lane + (j << 6);
      sum += y[b * CI + k] * aw[i * CI + k];
    }
    #pragma unroll
    for (int off = 32; off; off >>= 1) sum += __shfl_xor(sum, off);
    if (lane == 0) s[wid] = sum * 0.044194173824159216f + ab[i] + 1.0f;
  } else {
    const int idx = (blockIdx.x - 1024) * 256 + threadIdx.x;   // o*512+i
    const int i = idx & 511;
    const int o = idx >> 9;
    const float* p = wt + (size_t)idx * 9;
    float v[9];
    float sum = 0.f;
    #pragma unroll
    for (int t = 0; t < 9; ++t) { v[t] = p[t]; sum += v[t] * v[t]; }
    wsum[idx] = sum;
    // fragment-layout scatter: kg = t9*512 + i
    const int g = o >> 4, col = o & 15;
    const int kk = (i >> 5) & 1, k8 = (i >> 3) & 3, j = i & 7;
    const int lanepart = (((k8 << 4) | col) << 3) + j;
    #pragma unroll
    for (int t9 = 0; t9 < 9; ++t9) {
      const int t = t9 * 8 + (i >> 6);
      wbv[((((t * 32 + g) * 2 + kk) << 9) | lanepart)] = f2bf(v[t9]);
    }
  }
}

// fused: blocks 0..4095 -> xform (xs build + halo zero); 4096..5119 -> demod.
__global__ __launch_bounds__(256) void k_xfd(
    const float* __restrict__ x, const float* __restrict__ s,
    u16* __restrict__ xs, const float* __restrict__ wsum,
    float* __restrict__ d)
{
  __shared__ __align__(16) u16 lds[64 * 72];
  if (blockIdx.x >= 4096) {
    const int wid = (blockIdx.x - 4096) * 4 + (threadIdx.x >> 6);
    const int lane = threadIdx.x & 63;
    const int b = wid >> 9, o = wid & 511;
    float sum = 0.f;
    #pragma unroll
    for (int j = 0; j < 8; ++j) {
      const int i = lane + (j << 6);
      const float sv = s[b * CI + i];
      sum += wsum[o * CI + i] * sv * sv;
    }
    #pragma unroll
    for (int off = 32; off; off >>= 1) sum += __shfl_xor(sum, off);
    if (lane == 0) d[wid] = rsqrtf(sum + 1e-4f);
    return;
  }
  const int blk = blockIdx.x;          // ((b*64+h)*8 + ic)
  const int ic = blk & 7;
  const int h = (blk >> 3) & 63;
  const int b = blk >> 9;
  const int i0 = ic << 6;
  const int t = threadIdx.x;
  const int w = t & 63;
  const int i4 = t >> 6;
  #pragma unroll
  for (int p = 0; p < 16; ++p) {
    const int ii = i4 + (p << 2);
    const float xv = x[((size_t)(b * CI + i0 + ii) * HH + h) * WW + w];
    const float sv = s[b * CI + i0 + ii];
    lds[w * 72 + ii] = f2bf(xv * sv);
  }
  const uint4 z4 = {0u, 0u, 0u, 0u};
  if (t < 16) {
    const int wside = (t < 8) ? 0 : 65;
    const int q = t & 7;
    *(uint4*)&xs[((size_t)(b * HP + h + 1) * WP + wside) * CI + i0 + (q << 3)] = z4;
  }
  if (h == 0) {
    for (int idx = t; idx < 2 * 66 * 8; idx += 256) {
      const int row = (idx < 528) ? 0 : 65;
      const int rem = (idx < 528) ? idx : idx - 528;
      const int wz = rem >> 3;
      const int q = rem & 7;
      *(uint4*)&xs[((size_t)(b * HP + row) * WP + wz) * CI + i0 + (q << 3)] = z4;
    }
  }
  __syncthreads();
  const int w2 = t >> 2;
  const int q = t & 3;
  const uint4* src = (const uint4*)&lds[w2 * 72 + (q << 4)];
  const uint4 v0 = src[0];
  const uint4 v1 = src[1];
  u16* dst = xs + ((size_t)(b * HP + h + 1) * WP + (w2 + 1)) * CI + i0 + (q << 4);
  *(uint4*)dst = v0;
  *((uint4*)dst + 1) = v1;
}

// ---------------------------------------------------------------------------
// implicit-GEMM conv, A-DIRECT design: A fragments load global(L2)->VGPR
// (coalesced 1KB blocks via fragment-layout wbf), B stays in LDS (64 KB,
// double-buffered, XOR slot swizzle). Removes the 4x A-duplication that made
// LDS the binding pipe (192 KB -> 96 KB/tile/CU); MFMA now dominant.
// 2 phases/tile (one per kk-half), 1 barrier/tile (B-buffer WAR only).
// A prefetch: aK1(T) issued ph1 (used ph2), aK0(T+1) issued ph2 (used T+1
// ph1) - compiler inserts counted vmcnt for A-frag consumption (it tracks
// gload_lds builtins in the same counter). Cross-wave B certification:
// SB(T) [issued T-2 ph2, older than aK0(T-1)] is certified by every wave's
// own auto-wait at T-1 ph1, before the T-1 ph1-end barrier -> T ph1 reads
// safe. Belt-and-braces vmcnt(12) at ph2 end.
// ---------------------------------------------------------------------------
__global__ __launch_bounds__(512, 2) void k_conv(
    const u16* __restrict__ xs, const u16* __restrict__ wbf,
    const float* __restrict__ dmod, const float* __restrict__ bias,
    float* __restrict__ out)
{
  __shared__ __align__(16) u16 lB[2 * 16384];   // [buf][256 px][64 k] 64 KB

  const int blk = blockIdx.x;
  const int nt = blk & 15;
  const int mt = (blk >> 4) & 1;
  const int b  = blk >> 5;
  const int p0 = nt << 8;
  const int ob = mt << 8;

  const int tid = threadIdx.x;
  const int wid = tid >> 6;
  const int lane = tid & 63;
  const int col = lane & 15;
  const int k8  = lane >> 4;
  const int wr  = wid >> 2;          // wave M index (0..1)
  const int wc  = wid & 3;           // wave N index (0..3)

  const int gbase = (mt << 4) + (wr << 3);   // A fragment row-group base
  const u32 lane8 = (u32)(lane << 3);        // u16 offset within 1KB frag

  // B staging lane geometry (unchanged from champion)
  const int lr = lane >> 3;
  const int ls = lane & 7;
  const int swz = ls ^ lr;

  u32 boff[4], ldst[4];
  #pragma unroll
  for (int h2 = 0; h2 < 4; ++h2) {
    const int rowBase = ((h2 >> 1) << 7) + (wid << 4) + ((h2 & 1) << 3);
    const int rowIdx = rowBase + lr;
    const int p = p0 + rowIdx;
    boff[h2] = (u32)(((b * HP + (p >> 6)) * WP + (p & 63)) * 512 + (swz << 3));
    ldst[h2] = (u32)(rowBase << 6);
  }

  // B ds_read swizzled slot offsets: slot (kk*4+k8) ^ (row&7), row&7 == col&7
  const u32 sA0 = (u32)(((0 + k8) ^ (col & 7)) << 3);
  const u32 sA1 = (u32)(((4 + k8) ^ (col & 7)) << 3);
  const u32 bRead = (u32)((((wc << 6) + col) << 6));

  floatx4 acc[8][4];
  #pragma unroll
  for (int m = 0; m < 8; ++m)
    #pragma unroll
    for (int n = 0; n < 4; ++n)
      acc[m][n] = (floatx4){0.f, 0.f, 0.f, 0.f};

  short8 aK0[8], aK1[8], b0[2][2], b1[2][2];

#define GLBA(SET, T, KK) do {                                                 \
    _Pragma("unroll")                                                         \
    for (int mq = 0; mq < 8; ++mq)                                            \
      SET[mq] = *(const short8*)(wbf +                                        \
          (((u32)((T) * 32 + gbase + mq) * 2 + (KK)) << 9) + lane8);          \
  } while (0)

#define SB(TILE, H, BUF) do {                                                 \
    const int t_ = (TILE);                                                    \
    const int tap_ = t_ >> 3;                                                 \
    const int kh_ = tap_ / 3;                                                 \
    const int kw_ = tap_ - kh_ * 3;                                           \
    const u32 bt_ = (u32)(((kh_ * WP + kw_) << 9) + ((t_ & 7) << 6));         \
    gload16(xs + boff[(H)*2+0] + bt_, &lB[((BUF) << 14) + ldst[(H)*2+0]]);    \
    gload16(xs + boff[(H)*2+1] + bt_, &lB[((BUF) << 14) + ldst[(H)*2+1]]);    \
  } while (0)

#define READ_B(PB, NH, BV) do {                                               \
    _Pragma("unroll")                                                         \
    for (int nq = 0; nq < 2; ++nq) {                                          \
      BV[nq][0] = *(const short8*)((PB) + (NH) * 2048 + nq * 1024 + sA0);     \
      BV[nq][1] = *(const short8*)((PB) + (NH) * 2048 + nq * 1024 + sA1);     \
    }                                                                         \
  } while (0)

// 32 MFMA: one kk-half, all 8 m-frags x 4 n-frags
#define MFMA32(ASET, KK) do {                                                 \
    _Pragma("unroll")                                                         \
    for (int nq = 0; nq < 2; ++nq)                                            \
      _Pragma("unroll")                                                       \
      for (int mq = 0; mq < 8; ++mq)                                          \
        acc[mq][nq] = __builtin_amdgcn_mfma_f32_16x16x32_bf16(                \
            ASET[mq], b0[nq][KK], acc[mq][nq], 0, 0, 0);                      \
    _Pragma("unroll")                                                         \
    for (int nq = 0; nq < 2; ++nq)                                            \
      _Pragma("unroll")                                                       \
      for (int mq = 0; mq < 8; ++mq)                                          \
        acc[mq][2 + nq] = __builtin_amdgcn_mfma_f32_16x16x32_bf16(            \
            ASET[mq], b1[nq][KK], acc[mq][2 + nq], 0, 0, 0);                  \
  } while (0)

#define SBAR __builtin_amdgcn_s_barrier()
#define SCH0 __builtin_amdgcn_sched_barrier(0)
#define PRI1 __builtin_amdgcn_s_setprio(1)
#define PRI0 __builtin_amdgcn_s_setprio(0)

// MODE: 2 = full (tiles 0..69), 1 = tile 70, 0 = tile 71.
#define TILE2(T, C, MODE) do {                                                \
    const u16* pB = lB + ((C) << 14) + bRead;                                 \
    /* ph1: read B(T) [8 ds]; issue aK1(T) [8 glb]; MFMA kk=0 */              \
    READ_B(pB, 0, b0);                                                        \
    READ_B(pB, 1, b1);                                                        \
    GLBA(aK1, T, 1);                                                          \
    SCH0;                                                                     \
    PRI1; MFMA32(aK0, 0); PRI0;                                               \
    asm volatile("s_waitcnt lgkmcnt(0)" ::: "memory");                        \
    SCH0;                                                                     \
    SBAR;                                                                     \
    /* ph2: stage SB(T+2) -> buf C (B(T) reads barrier-certified done);       \
       issue aK0(T+1); MFMA kk=1; certify SB(T+1) for next tile */            \
    if (MODE == 2) { SB((T) + 2, 0, C); SB((T) + 2, 1, C); }                  \
    if (MODE >= 1) GLBA(aK0, (T) + 1, 0);                                     \
    SCH0;                                                                     \
    PRI1; MFMA32(aK1, 1); PRI0;                                               \
    if (MODE == 2)      asm volatile("s_waitcnt vmcnt(12)" ::: "memory");     \
    else if (MODE == 1) asm volatile("s_waitcnt vmcnt(8)" ::: "memory");      \
    SCH0;                                                                     \
  } while (0)

  // prologue: SB(0)->buf0 [4], SB(1)->buf1 [4], aK0(0) [8];
  // vmcnt(12) certifies SB(0) (12 newer = SB(1)4 + aK0 8); barrier.
  SB(0, 0, 0); SB(0, 1, 0);
  SB(1, 0, 1); SB(1, 1, 1);
  GLBA(aK0, 0, 0);
  asm volatile("s_waitcnt vmcnt(12)" ::: "memory");
  SCH0;
  SBAR;

  for (int j = 0; j < 35; ++j) {
    TILE2(2 * j,     0, 2);
    TILE2(2 * j + 1, 1, 2);
  }
  TILE2(70, 0, 1);
  TILE2(71, 1, 0);

#undef GLBA
#undef SB
#undef READ_B
#undef MFMA32
#undef TILE2
#undef SBAR
#undef SCH0
#undef PRI1
#undef PRI0

  // epilogue: out = acc * d[b,o] + bias[o]; C/D: col=lane&15, row=(lane>>4)*4+r
  #pragma unroll
  for (int m = 0; m < 8; ++m) {
    #pragma unroll
    for (int r = 0; r < 4; ++r) {
      const int o = ob + (wr << 7) + (m << 4) + (k8 << 2) + r;
      const float dm = dmod[b * CO + o];
      const float bs = bias[o];
      float* po = out + (((size_t)(b * CO + o)) << 12) + p0 + (wc << 6);
      #pragma unroll
      for (int n = 0; n < 4; ++n)
        po[(n << 4) + col] = acc[m][n][r] * dm + bs;
    }
  }
}

extern "C" void kernel_launch(void* const* d_in, const int* in_sizes, int n_in,
                              void* d_out, int out_size, void* d_ws, size_t ws_size,
                              hipStream_t stream) {
  const float* x    = (const float*)d_in[0];
  const float* y    = (const float*)d_in[1];
  const float* aw   = (const float*)d_in[2];
  const float* ab   = (const float*)d_in[3];
  const float* wt   = (const float*)d_in[4];
  const float* bias = (const float*)d_in[5];
  float* out = (float*)d_out;

  char* ws = (char*)d_ws;
  const size_t XS_BYTES = (size_t)NB * HP * WP * CI * 2;     // 35,684,352
  const size_t WB_BYTES = (size_t)72 * 32 * 2 * 512 * 2;     //  4,718,592
  const size_t WS_BYTES = (size_t)CO * CI * 4;               //  1,048,576
  u16* xsb    = (u16*)ws;
  u16* wbuf   = (u16*)(ws + XS_BYTES);
  float* wsum = (float*)(ws + XS_BYTES + WB_BYTES);
  float* sbuf = (float*)(ws + XS_BYTES + WB_BYTES + WS_BYTES);
  float* dbuf = sbuf + NB * CI;

  k_prep1<<<dim3(2048), dim3(256), 0, stream>>>(y, aw, ab, sbuf, wt, wsum, wbuf);
  k_xfd  <<<dim3(5120), dim3(256), 0, stream>>>(x, sbuf, xsb, wsum, dbuf);
  k_conv <<<dim3(256), dim3(512), 0, stream>>>(xsb, wbuf, dbuf, bias, out);
}

// Round 18
// 153.539 us; speedup vs baseline: 1.0765x; 1.0765x over previous
//
#include <hip/hip_runtime.h>

typedef __attribute__((ext_vector_type(8))) short short8;
typedef __attribute__((ext_vector_type(4))) float floatx4;
typedef unsigned short u16;
typedef unsigned int u32;

#define NB 8
#define CI 512
#define CO 512
#define HH 64
#define WW 64
#define HP 66
#define WP 66
#define BK 64

__device__ __forceinline__ u16 f2bf(float f) {
  u32 u = __builtin_bit_cast(u32, f);
  u += 0x7fffu + ((u >> 16) & 1u);
  return (u16)(u >> 16);
}

__device__ __forceinline__ void gload16(const void* g, void* l) {
  __builtin_amdgcn_global_load_lds(
      (const __attribute__((address_space(1))) unsigned int*)g,
      (__attribute__((address_space(3))) unsigned int*)l, 16, 0, 0);
}

// fused prep1: blocks 0..1023 -> style s[b,i]; blocks 1024..2047 -> wprep.
__global__ __launch_bounds__(256) void k_prep1(
    const float* __restrict__ y, const float* __restrict__ aw,
    const float* __restrict__ ab, float* __restrict__ s,
    const float* __restrict__ wt, float* __restrict__ wsum,
    u16* __restrict__ wbv)
{
  if (blockIdx.x < 1024) {
    const int wid = blockIdx.x * 4 + (threadIdx.x >> 6);
    const int lane = threadIdx.x & 63;
    const int b = wid >> 9, i = wid & 511;
    float sum = 0.f;
    #pragma unroll
    for (int j = 0; j < 8; ++j) {
      const int k = lane + (j << 6);
      sum += y[b * CI + k] * aw[i * CI + k];
    }
    #pragma unroll
    for (int off = 32; off; off >>= 1) sum += __shfl_xor(sum, off);
    if (lane == 0) s[wid] = sum * 0.044194173824159216f + ab[i] + 1.0f;
  } else {
    const int idx = (blockIdx.x - 1024) * 256 + threadIdx.x;   // o*512+i
    const int i = idx & 511;
    const int o = idx >> 9;
    const float* p = wt + (size_t)idx * 9;
    float v[9];
    float sum = 0.f;
    #pragma unroll
    for (int t = 0; t < 9; ++t) { v[t] = p[t]; sum += v[t] * v[t]; }
    wsum[idx] = sum;
    #pragma unroll
    for (int t = 0; t < 9; ++t) wbv[(((o * 9 + t) << 9) | i)] = f2bf(v[t]);
  }
}

// fused: blocks 0..4095 -> xform (xs build + halo zero); 4096..5119 -> demod.
__global__ __launch_bounds__(256) void k_xfd(
    const float* __restrict__ x, const float* __restrict__ s,
    u16* __restrict__ xs, const float* __restrict__ wsum,
    float* __restrict__ d)
{
  __shared__ __align__(16) u16 lds[64 * 72];
  if (blockIdx.x >= 4096) {
    const int wid = (blockIdx.x - 4096) * 4 + (threadIdx.x >> 6);
    const int lane = threadIdx.x & 63;
    const int b = wid >> 9, o = wid & 511;
    float sum = 0.f;
    #pragma unroll
    for (int j = 0; j < 8; ++j) {
      const int i = lane + (j << 6);
      const float sv = s[b * CI + i];
      sum += wsum[o * CI + i] * sv * sv;
    }
    #pragma unroll
    for (int off = 32; off; off >>= 1) sum += __shfl_xor(sum, off);
    if (lane == 0) d[wid] = rsqrtf(sum + 1e-4f);
    return;
  }
  const int blk = blockIdx.x;          // ((b*64+h)*8 + ic)
  const int ic = blk & 7;
  const int h = (blk >> 3) & 63;
  const int b = blk >> 9;
  const int i0 = ic << 6;
  const int t = threadIdx.x;
  const int w = t & 63;
  const int i4 = t >> 6;
  #pragma unroll
  for (int p = 0; p < 16; ++p) {
    const int ii = i4 + (p << 2);
    const float xv = x[((size_t)(b * CI + i0 + ii) * HH + h) * WW + w];
    const float sv = s[b * CI + i0 + ii];
    lds[w * 72 + ii] = f2bf(xv * sv);
  }
  const uint4 z4 = {0u, 0u, 0u, 0u};
  if (t < 16) {
    const int wside = (t < 8) ? 0 : 65;
    const int q = t & 7;
    *(uint4*)&xs[((size_t)(b * HP + h + 1) * WP + wside) * CI + i0 + (q << 3)] = z4;
  }
  if (h == 0) {
    for (int idx = t; idx < 2 * 66 * 8; idx += 256) {
      const int row = (idx < 528) ? 0 : 65;
      const int rem = (idx < 528) ? idx : idx - 528;
      const int wz = rem >> 3;
      const int q = rem & 7;
      *(uint4*)&xs[((size_t)(b * HP + row) * WP + wz) * CI + i0 + (q << 3)] = z4;
    }
  }
  __syncthreads();
  const int w2 = t >> 2;
  const int q = t & 3;
  const uint4* src = (const uint4*)&lds[w2 * 72 + (q << 4)];
  const uint4 v0 = src[0];
  const uint4 v1 = src[1];
  u16* dst = xs + ((size_t)(b * HP + h + 1) * WP + (w2 + 1)) * CI + i0 + (q << 4);
  *(uint4*)dst = v0;
  *((uint4*)dst + 1) = v1;
}

// ---------------------------------------------------------------------------
// implicit-GEMM conv — CHAMPION (R13): leveled 4-phase schedule, m201 wait
// discipline (post-barrier lgkmcnt(0)+sched_barrier), counted vmcnt(6)/(4),
// fine-grained half-stage interleave, XOR slot swizzle both-sides, natural
// block order. Measured: 136.9 µs, MfmaUtil 47.6%, bank conflicts 0.
// Ablation table (9 variants incl. A-direct dataflow, R17) documented in
// session log: this is the floor of this structure — LDS instr throughput
// (~2570 cyc/tile) + MFMA (2483) at ~60% overlap. A-direct (L2->VGPR A)
// regressed because per-CU L2 BW (~56 B/cyc) < LDS BW (85-128 B/cyc).
// ---------------------------------------------------------------------------
__global__ __launch_bounds__(512, 2) void k_conv(
    const u16* __restrict__ xs, const u16* __restrict__ wb,
    const float* __restrict__ dmod, const float* __restrict__ bias,
    float* __restrict__ out)
{
  __shared__ __align__(16) u16 lA[2 * 16384];
  __shared__ __align__(16) u16 lB[2 * 16384];

  const int blk = blockIdx.x;
  const int nt = blk & 15;
  const int mt = (blk >> 4) & 1;
  const int b  = blk >> 5;
  const int ob = mt << 8;
  const int p0 = nt << 8;

  const int tid = threadIdx.x;
  const int wid = tid >> 6;
  const int lane = tid & 63;
  const int col = lane & 15;
  const int k8  = lane >> 4;
  const int wr  = wid >> 2;          // wave M index (0..1)
  const int wc  = wid & 3;           // wave N index (0..3)

  const int lr = lane >> 3;
  const int ls = lane & 7;
  const int swz = ls ^ lr;

  u32 aoff[4], boff[4], ldst[4];
  #pragma unroll
  for (int h2 = 0; h2 < 4; ++h2) {
    const int rowBase = ((h2 >> 1) << 7) + (wid << 4) + ((h2 & 1) << 3);
    const int rowIdx = rowBase + lr;
    aoff[h2] = (u32)((ob + rowIdx) * 4608 + (swz << 3));
    const int p = p0 + rowIdx;
    boff[h2] = (u32)(((b * HP + (p >> 6)) * WP + (p & 63)) * 512 + (swz << 3));
    ldst[h2] = (u32)(rowBase << 6);
  }

  const u32 sA0 = (u32)(((0 + k8) ^ (col & 7)) << 3);
  const u32 sA1 = (u32)(((4 + k8) ^ (col & 7)) << 3);
  const u32 aRead = (u32)((((wr << 7) + col) << 6));
  const u32 bRead = (u32)((((wc << 6) + col) << 6));

  floatx4 acc[8][4];
  #pragma unroll
  for (int m = 0; m < 8; ++m)
    #pragma unroll
    for (int n = 0; n < 4; ++n)
      acc[m][n] = (floatx4){0.f, 0.f, 0.f, 0.f};

  short8 a0[4][2], b0[2][2], b1[2][2];

#define SA(TILE, H, BUF) do {                                                 \
    const u32 at_ = (u32)((TILE) << 6);                                       \
    gload16(wb + aoff[(H)*2+0] + at_, &lA[((BUF) << 14) + ldst[(H)*2+0]]);    \
    gload16(wb + aoff[(H)*2+1] + at_, &lA[((BUF) << 14) + ldst[(H)*2+1]]);    \
  } while (0)

#define SB(TILE, H, BUF) do {                                                 \
    const int t_ = (TILE);                                                    \
    const int tap_ = t_ >> 3;                                                 \
    const int kh_ = tap_ / 3;                                                 \
    const int kw_ = tap_ - kh_ * 3;                                           \
    const u32 bt_ = (u32)(((kh_ * WP + kw_) << 9) + ((t_ & 7) << 6));         \
    gload16(xs + boff[(H)*2+0] + bt_, &lB[((BUF) << 14) + ldst[(H)*2+0]]);    \
    gload16(xs + boff[(H)*2+1] + bt_, &lB[((BUF) << 14) + ldst[(H)*2+1]]);    \
  } while (0)

#define READ_A(PA, MH) do {                                                   \
    _Pragma("unroll")                                                         \
    for (int mq = 0; mq < 4; ++mq) {                                          \
      a0[mq][0] = *(const short8*)((PA) + (MH) * 4096 + mq * 1024 + sA0);     \
      a0[mq][1] = *(const short8*)((PA) + (MH) * 4096 + mq * 1024 + sA1);     \
    }                                                                         \
  } while (0)

#define READ_B(PB, NH, BV) do {                                               \
    _Pragma("unroll")                                                         \
    for (int nq = 0; nq < 2; ++nq) {                                          \
      BV[nq][0] = *(const short8*)((PB) + (NH) * 2048 + nq * 1024 + sA0);     \
      BV[nq][1] = *(const short8*)((PB) + (NH) * 2048 + nq * 1024 + sA1);     \
    }                                                                         \
  } while (0)

#define MFMA_Q(MH, NH, BV) do {                                               \
    _Pragma("unroll")                                                         \
    for (int kk = 0; kk < 2; ++kk)                                            \
      _Pragma("unroll")                                                       \
      for (int nq = 0; nq < 2; ++nq)                                          \
        _Pragma("unroll")                                                     \
        for (int mq = 0; mq < 4; ++mq)                                        \
          acc[(MH)*4+mq][(NH)*2+nq] = __builtin_amdgcn_mfma_f32_16x16x32_bf16(\
              a0[mq][kk], BV[nq][kk], acc[(MH)*4+mq][(NH)*2+nq], 0, 0, 0);    \
  } while (0)

#define SBAR __builtin_amdgcn_s_barrier()
#define SCH0 __builtin_amdgcn_sched_barrier(0)
#define PRI1 __builtin_amdgcn_s_setprio(1)
#define PRI0 __builtin_amdgcn_s_setprio(0)
#define LGKM0 do { asm volatile("s_waitcnt lgkmcnt(0)" ::: "memory"); SCH0; } while (0)

// MODE: 2 = full (tiles 0..69), 1 = tile 70, 0 = tile 71.
#define TILE4(T, C, MODE) do {                                                \
    const u16* pA  = lA + ((C) << 14) + aRead;                                \
    const u16* pB  = lB + ((C) << 14) + bRead;                                \
    const u16* pBn = lB + ((1 - (C)) << 14) + bRead;                          \
    /* ph1: 8 reads (A0); stage SA(T+1,h0); MFMA Q(0,0) on pre-read b0 */     \
    READ_A(pA, 0);                                                            \
    SCH0; if (MODE >= 1) SA((T) + 1, 0, 1 - (C));                             \
    SBAR; LGKM0; PRI1; MFMA_Q(0, 0, b0); PRI0; SBAR;                          \
    /* ph2: 4 reads (B1); stage SA(T+1,h1) */                                 \
    READ_B(pB, 1, b1);                                                        \
    SCH0; if (MODE >= 1) SA((T) + 1, 1, 1 - (C));                             \
    SBAR; LGKM0; PRI1; MFMA_Q(0, 1, b1); PRI0; SBAR;                          \
    /* ph3: 8 reads (A1); stage SB(T+2,h0); vmcnt certifies B(T+1) */         \
    READ_A(pA, 1);                                                            \
    SCH0; if (MODE == 2) SB((T) + 2, 0, C);                                   \
    if (MODE == 2)      asm volatile("s_waitcnt vmcnt(6)" ::: "memory");      \
    else if (MODE == 1) asm volatile("s_waitcnt vmcnt(4)" ::: "memory");      \
    SBAR; LGKM0; PRI1; MFMA_Q(1, 1, b1); PRI0; SBAR;                          \
    /* ph4: stage SB(T+2,h1); vmcnt certifies A(T+1); MFMA Q(1,0);            \
       then pre-read NEXT tile's B0 (b0 dead after this MFMA) */              \
    SCH0; if (MODE == 2) SB((T) + 2, 1, C);                                   \
    if (MODE == 2)      asm volatile("s_waitcnt vmcnt(4)" ::: "memory");      \
    else if (MODE == 1) asm volatile("s_waitcnt vmcnt(0)" ::: "memory");      \
    SBAR; LGKM0; PRI1; MFMA_Q(1, 0, b0); PRI0;                                \
    if (MODE >= 1) READ_B(pBn, 0, b0);                                        \
    SBAR;                                                                     \
  } while (0)

  // prologue: SB(0), SA(0) [oldest 8], SB(1) [newest 4];
  // vmcnt(4) completes SB(0)+SA(0), leaves SB(1) in flight (steady invariant).
  SB(0, 0, 0); SB(0, 1, 0);
  SA(0, 0, 0); SA(0, 1, 0);
  SB(1, 0, 1); SB(1, 1, 1);
  asm volatile("s_waitcnt vmcnt(4)" ::: "memory");
  SCH0;
  SBAR;
  {
    const u16* pB0 = lB + bRead;
    READ_B(pB0, 0, b0);              // pre-read B0 of tile 0
  }

  for (int j = 0; j < 35; ++j) {
    TILE4(2 * j,     0, 2);
    TILE4(2 * j + 1, 1, 2);
  }
  TILE4(70, 0, 1);
  TILE4(71, 1, 0);

#undef SA
#undef SB
#undef READ_A
#undef READ_B
#undef MFMA_Q
#undef TILE4
#undef SBAR
#undef SCH0
#undef PRI1
#undef PRI0
#undef LGKM0

  // epilogue: out = acc * d[b,o] + bias[o]; C/D: col=lane&15, row=(lane>>4)*4+r
  #pragma unroll
  for (int m = 0; m < 8; ++m) {
    #pragma unroll
    for (int r = 0; r < 4; ++r) {
      const int o = ob + (wr << 7) + (m << 4) + (k8 << 2) + r;
      const float dm = dmod[b * CO + o];
      const float bs = bias[o];
      float* po = out + (((size_t)(b * CO + o)) << 12) + p0 + (wc << 6);
      #pragma unroll
      for (int n = 0; n < 4; ++n)
        po[(n << 4) + col] = acc[m][n][r] * dm + bs;
    }
  }
}

extern "C" void kernel_launch(void* const* d_in, const int* in_sizes, int n_in,
                              void* d_out, int out_size, void* d_ws, size_t ws_size,
                              hipStream_t stream) {
  const float* x    = (const float*)d_in[0];
  const float* y    = (const float*)d_in[1];
  const float* aw   = (const float*)d_in[2];
  const float* ab   = (const float*)d_in[3];
  const float* wt   = (const float*)d_in[4];
  const float* bias = (const float*)d_in[5];
  float* out = (float*)d_out;

  char* ws = (char*)d_ws;
  const size_t XS_BYTES = (size_t)NB * HP * WP * CI * 2;     // 35,684,352
  const size_t WB_BYTES = (size_t)CO * 9 * CI * 2;           //  4,718,592
  const size_t WS_BYTES = (size_t)CO * CI * 4;               //  1,048,576
  u16* xsb    = (u16*)ws;
  u16* wbuf   = (u16*)(ws + XS_BYTES);
  float* wsum = (float*)(ws + XS_BYTES + WB_BYTES);
  float* sbuf = (float*)(ws + XS_BYTES + WB_BYTES + WS_BYTES);
  float* dbuf = sbuf + NB * CI;

  k_prep1<<<dim3(2048), dim3(256), 0, stream>>>(y, aw, ab, sbuf, wt, wsum, wbuf);
  k_xfd  <<<dim3(5120), dim3(256), 0, stream>>>(x, sbuf, xsb, wsum, dbuf);
  k_conv <<<dim3(256), dim3(512), 0, stream>>>(xsb, wbuf, dbuf, bias, out);
}